// Round 7
// baseline (54.689 us; speedup 1.0000x reference)
//
#include <hip/hip_runtime.h>
#include <math.h>

#define N_IMG 32
#define L_ROI 4096
#define M_GT  128
#define C_CLS 80
#define IOU_T 0.5f
#define NSEG  16          // L_ROI / 256 segments per image

// ---------------------------------------------------------------------------
// K1: per-roi IoU argmax vs all gt (LDS-staged). Each block owns one
//     256-roi segment and compacts its positives (roi-ordered) into
//     plist[n][seg][*] plus an unconditional count cnt[n][seg].
//     Block 0 zeroes K2's 32-arrival ticket (stream order -> safe).
// ---------------------------------------------------------------------------
__global__ __launch_bounds__(256) void k_match(
    const float4* __restrict__ rois,      // [N*L]
    const float4* __restrict__ gt_boxes,  // [N*M]
    const int*    __restrict__ gt_cls,    // [N*M]
    int* __restrict__ plist,              // [N][NSEG][256] packed (l<<7|lab)
    int* __restrict__ cnt,                // [N][NSEG]
    int* __restrict__ ticket)             // [1] -> 0
{
    __shared__ float4 sgt[M_GT];
    __shared__ float  sarea[M_GT];
    __shared__ int    swt[4];

    const int n   = blockIdx.x >> 4;
    const int seg = blockIdx.x & 15;
    const int t   = threadIdx.x;
    if (blockIdx.x == 0 && t == 0) *ticket = 0;
    if (t < M_GT) {
        float4 g = gt_boxes[n * M_GT + t];
        sgt[t]   = g;
        sarea[t] = (g.z - g.x) * (g.w - g.y);
    }
    __syncthreads();

    const int l = seg * 256 + t;
    float4 r = rois[(size_t)n * L_ROI + l];
    float ar = (r.z - r.x) * (r.w - r.y);

    float best = -1.0f;
    int   bi   = 0;
    #pragma unroll 4
    for (int m = 0; m < M_GT; ++m) {
        float4 g = sgt[m];
        float ix = fminf(r.z, g.z) - fmaxf(r.x, g.x);
        float iy = fminf(r.w, g.w) - fmaxf(r.y, g.y);
        ix = fmaxf(ix, 0.0f);
        iy = fmaxf(iy, 0.0f);
        float inter = ix * iy;
        float iou   = inter / (ar + sarea[m] - inter);
        if (iou > best) { best = iou; bi = m; }   // strict >: first-occurrence argmax
    }
    const int pos  = (best >= IOU_T) ? 1 : 0;
    const int lab  = gt_cls[n * M_GT + bi];
    const int lane = t & 63;
    const int wv   = t >> 6;

    unsigned long long mask = __ballot(pos);
    if (lane == 0) swt[wv] = (int)__popcll(mask);
    __syncthreads();
    int woff = 0;
    for (int w = 0; w < wv; ++w) woff += swt[w];
    if (pos) {
        int pref = (int)__popcll(mask & ((1ull << lane) - 1ull));
        plist[((n * NSEG + seg) << 8) + woff + pref] = (l << 7) | lab;
    }
    if (t == 0) cnt[n * NSEG + seg] = swt[0] + swt[1] + swt[2] + swt[3];
}

// ---------------------------------------------------------------------------
// K2: one 1024-thread block per image. Stage the image's ordered positive
//     list into LDS once; 16 waves x 5 classes each: take first sn class-c
//     positives in roi order (ballot bit order == roi order), wave-wide
//     80-class logsumexp per taken roi. Block-local per-image mean, then
//     32-arrival ticket; last block sums the 32 images in fixed order.
// ---------------------------------------------------------------------------
__global__ __launch_bounds__(1024) void k_sel2(
    const float* __restrict__ cls_scores,  // [N,L,C]
    const int*   __restrict__ plist,
    const int*   __restrict__ cnt,
    float* __restrict__ per_img,           // [N]
    int*   __restrict__ ticket,            // [1] == 0 at kernel start
    float* __restrict__ out)
{
    __shared__ int   ldslist[L_ROI];
    __shared__ int   pref[NSEG + 1];
    __shared__ float snll[C_CLS];
    __shared__ int   scnt[C_CLS];
    __shared__ int   amlast;

    const int n    = blockIdx.x;
    const int t    = threadIdx.x;
    const int lane = t & 63;
    const int wv   = t >> 6;            // 16 waves

    // segment-count prefix (wave 0)
    if (wv == 0) {
        int v = (lane < NSEG) ? cnt[n * NSEG + lane] : 0;
        int incl = v;
        #pragma unroll
        for (int o = 1; o < NSEG; o <<= 1) {
            int y = __shfl_up(incl, o);
            if (lane >= o) incl += y;
        }
        if (lane < NSEG) pref[lane] = incl - v;
        if (lane == NSEG - 1) pref[NSEG] = incl;
    }
    __syncthreads();

    // stage ordered positive list: wave w copies segment w
    {
        const int base = pref[wv];
        const int segc = pref[wv + 1] - base;
        const int* src = plist + (((size_t)n * NSEG + wv) << 8);
        for (int i = lane; i < segc; i += 64) ldslist[base + i] = src[i];
    }
    __syncthreads();

    const int np = pref[NSEG];
    const int sn = max(1, (np + C_CLS - 1) / C_CLS);  // ceil(max(1, np/C))

    // each wave: 5 classes (c = wv + 16*ci)
    for (int ci = 0; ci < 5; ++ci) {
        const int c = wv + (ci << 4);
        float lsum = 0.0f;
        int taken = 0;
        for (int base = 0; base < np && taken < sn; base += 64) {
            const int e = (base + lane < np) ? ldslist[base + lane] : -1;
            unsigned long long m = __ballot(e >= 0 && (e & 127) == c);
            while (m && taken < sn) {
                const int src = __ffsll(m) - 1;
                m &= m - 1;
                const int roi = __shfl(e, src) >> 7;

                const float* rp = cls_scores + ((size_t)n * L_ROI + roi) * C_CLS;
                float v0 = rp[lane];
                float v1 = (lane < C_CLS - 64) ? rp[64 + lane] : -INFINITY;
                float mx = fmaxf(v0, v1);
                #pragma unroll
                for (int o = 32; o; o >>= 1) mx = fmaxf(mx, __shfl_xor(mx, o));
                float s = expf(v0 - mx) + ((lane < C_CLS - 64) ? expf(v1 - mx) : 0.0f);
                #pragma unroll
                for (int o = 32; o; o >>= 1) s += __shfl_xor(s, o);
                const float logZ = mx + logf(s);
                const float sc = (c < 64) ? __shfl(v0, c) : __shfl(v1, c - 64);
                lsum += logZ - sc;
                ++taken;
            }
        }
        if (lane == 0) { snll[c] = lsum; scnt[c] = taken; }
    }
    __syncthreads();

    // block-local per-image mean
    if (wv == 0) {
        float v = snll[lane] + ((lane < C_CLS - 64) ? snll[64 + lane] : 0.0f);
        int   q = scnt[lane] + ((lane < C_CLS - 64) ? scnt[64 + lane] : 0);
        #pragma unroll
        for (int o = 32; o; o >>= 1) { v += __shfl_xor(v, o); q += __shfl_xor(q, o); }
        if (lane == 0) per_img[n] = v / (float)q;
    }
    __syncthreads();

    // 32-arrival ticket; last block reduces the 32 images (fixed order)
    if (t == 0) {
        __threadfence();  // release per_img[n]
        int tk = __hip_atomic_fetch_add(ticket, 1, __ATOMIC_ACQ_REL,
                                        __HIP_MEMORY_SCOPE_AGENT);
        amlast = (tk == N_IMG - 1);
    }
    __syncthreads();
    if (amlast && t < 64) {
        __threadfence();  // acquire all blocks' per_img
        float v = (lane < N_IMG) ? per_img[lane] : 0.0f;
        #pragma unroll
        for (int o = 32; o; o >>= 1) v += __shfl_xor(v, o);
        if (lane == 0) out[0] = v;
    }
}

extern "C" void kernel_launch(void* const* d_in, const int* in_sizes, int n_in,
                              void* d_out, int out_size, void* d_ws, size_t ws_size,
                              hipStream_t stream) {
    const float4* rois       = (const float4*)d_in[0];
    const float*  cls_scores = (const float*)d_in[1];
    // d_in[2] = bbox_deltas: only feeds 0.0 * chosen.sum() -> never read.
    const float4* gt_boxes   = (const float4*)d_in[3];
    const int*    gt_clses   = (const int*)d_in[4];
    float* out = (float*)d_out;

    char* ws = (char*)d_ws;
    int*   ticket  = (int*)(ws + 0);        // 1 int, zeroed by k_match block 0
    int*   cnt     = (int*)(ws + 128);      // N*NSEG ints (2 KiB)
    float* per_img = (float*)(ws + 4096);   // N floats
    int*   plist   = (int*)(ws + 32768);    // N*L ints (512 KiB)

    k_match<<<N_IMG * NSEG, 256, 0, stream>>>(
        rois, gt_boxes, gt_clses, plist, cnt, ticket);
    k_sel2<<<N_IMG, 1024, 0, stream>>>(
        cls_scores, plist, cnt, per_img, ticket, out);
}